// Round 3
// baseline (5749.878 us; speedup 1.0000x reference)
//
#include <hip/hip_runtime.h>
#include <hip/hip_bf16.h>

typedef __hip_bfloat16 bf16;

#define TM 16
#define KC 20

__device__ __forceinline__ float b2f(bf16 x) { return __bfloat162float(x); }
__device__ __forceinline__ bf16 f2b(float x) { return __float2bfloat16(x); }

// out[m, c] = sum_k X[m,k] * W[c,k] (+ bias[c]),  c in [0,300), K = 300 or 600.
// GATHER: X row r comes from emb[wid[m0+r]] (f32, K=300). Else Xsrc (bf16 ws).
// W, bias are f32 (input dtype). Output is bf16 (ws intermediate only).
// Block: 256 threads, TM=16 rows, all 300 cols. Thread (cid=tid&127, rg=tid>>7)
// computes rows rg*8..rg*8+7 for cols cid, cid+128, cid+256(<300).
template <int K, bool GATHER, bool BIAS>
__global__ __launch_bounds__(256) void gemm_kernel(
    const bf16* __restrict__ Xsrc, const int* __restrict__ wid,
    const float* __restrict__ emb, const float* __restrict__ W,
    const float* __restrict__ bias, bf16* __restrict__ out)
{
    __shared__ float Xs[K][TM];          // transposed: Xs[k][r]
    __shared__ float Ws[300][KC + 1];    // +1 pad: stride 21 coprime with 32 banks

    const int  tid = threadIdx.x;
    const long m0  = (long)blockIdx.x * TM;

    // ---- stage X tile (transposed) ----
    for (int idx = tid; idx < TM * K; idx += 256) {
        const int k = idx >> 4;          // requires TM==16
        const int r = idx & 15;
        float v;
        if (GATHER) v = emb[(long)wid[m0 + r] * 300 + k];
        else        v = b2f(Xsrc[(m0 + r) * (long)K + k]);
        Xs[k][r] = v;
    }

    const int cid = tid & 127;
    const int r0  = (tid >> 7) * 8;
    const int c0 = cid, c1 = cid + 128, c2 = cid + 256;   // c2 valid iff cid<44

    float acc[3][8];
#pragma unroll
    for (int ci = 0; ci < 3; ci++)
#pragma unroll
        for (int j = 0; j < 8; j++) acc[ci][j] = 0.f;

    for (int kc = 0; kc < K; kc += KC) {
        __syncthreads();  // Xs staged (first iter) / prev Ws reads done
        // ---- stage W chunk: Ws[c][kk] = W[c*K + kc+kk] ----
        for (int idx = tid; idx < 300 * KC; idx += 256) {
            const int c  = idx / KC;
            const int kk = idx - c * KC;
            Ws[c][kk] = W[(long)c * K + kc + kk];
        }
        __syncthreads();

#pragma unroll
        for (int kk = 0; kk < KC; kk++) {
            // ev[0..7] = Xs[kc+kk][r0 .. r0+7]  (two ds_read_b128, broadcast)
            const float4* p = (const float4*)&Xs[kc + kk][r0];
            const float4  a = p[0], b = p[1];
            const float ev[8] = {a.x, a.y, a.z, a.w, b.x, b.y, b.z, b.w};

            {
                const float w = Ws[c0][kk];
#pragma unroll
                for (int j = 0; j < 8; j++) acc[0][j] += ev[j] * w;
            }
            {
                const float w = Ws[c1][kk];
#pragma unroll
                for (int j = 0; j < 8; j++) acc[1][j] += ev[j] * w;
            }
            if (c2 < 300) {
                const float w = Ws[c2][kk];
#pragma unroll
                for (int j = 0; j < 8; j++) acc[2][j] += ev[j] * w;
            }
        }
    }

    // ---- epilogue: bias + store (coalesced in c across the wave) ----
#pragma unroll
    for (int ci = 0; ci < 3; ci++) {
        const int c = (ci == 0) ? c0 : (ci == 1) ? c1 : c2;
        if (c >= 300) continue;
        const float bv = BIAS ? bias[c] : 0.f;
#pragma unroll
        for (int j = 0; j < 8; j++)
            out[(m0 + r0 + j) * 300 + c] = f2b(acc[ci][j] + bv);
    }
}

// One 64-lane wave per batch row: feat = sigmoid(roots[b, 0:600]);
// logits[r] = feat . W_cls[r] + b_cls[r]; out = log_softmax(logits).  OUT IS F32.
__global__ __launch_bounds__(64) void cls_kernel(
    const bf16* __restrict__ roots, const float* __restrict__ W_cls,
    const float* __restrict__ b_cls, float* __restrict__ out)
{
    const int b    = blockIdx.x;
    const int lane = threadIdx.x;
    const bf16* row = roots + (long)b * 600;

    float a0 = 0.f, a1 = 0.f, a2 = 0.f;
#pragma unroll
    for (int i = 0; i < 10; i++) {
        const int k = lane + 64 * i;
        if (k < 600) {
            const float f = 1.f / (1.f + __expf(-b2f(row[k])));
            a0 += f * W_cls[k];
            a1 += f * W_cls[600 + k];
            a2 += f * W_cls[1200 + k];
        }
    }
#pragma unroll
    for (int off = 32; off > 0; off >>= 1) {
        a0 += __shfl_down(a0, off);
        a1 += __shfl_down(a1, off);
        a2 += __shfl_down(a2, off);
    }
    if (lane == 0) {
        const float l0 = a0 + b_cls[0];
        const float l1 = a1 + b_cls[1];
        const float l2 = a2 + b_cls[2];
        const float m  = fmaxf(l0, fmaxf(l1, l2));
        const float s  = __expf(l0 - m) + __expf(l1 - m) + __expf(l2 - m);
        const float ls = m + __logf(s);
        out[b * 3 + 0] = l0 - ls;
        out[b * 3 + 1] = l1 - ls;
        out[b * 3 + 2] = l2 - ls;
    }
}

extern "C" void kernel_launch(void* const* d_in, const int* in_sizes, int n_in,
                              void* d_out, int out_size, void* d_ws, size_t ws_size,
                              hipStream_t stream)
{
    const int*   wid    = (const int*)d_in[0];     // (512, 2, 256) int32
    const float* emb    = (const float*)d_in[1];   // (50000, 300) f32
    const float* W_leaf = (const float*)d_in[2];   // (300, 300) f32
    const float* W_h    = (const float*)d_in[3];   // (300, 600) f32
    const float* b_h    = (const float*)d_in[4];   // (300,) f32
    const float* W_cls  = (const float*)d_in[5];   // (3, 600) f32
    const float* b_cls  = (const float*)d_in[6];   // (3,) f32
    float* outp = (float*)d_out;                   // (512, 3) f32

    (void)in_sizes; (void)n_in; (void)out_size; (void)ws_size;

    char* ws = (char*)d_ws;
    bf16* hA = (bf16*)ws;                              // 262144 x 300 bf16 (157.3 MB)
    bf16* hB = (bf16*)(ws + 262144L * 300 * 2);        // 131072 x 300 bf16 (78.6 MB)

    // Leaf: h0[m, :] = W_leaf @ emb[wid[m]],  M = 1024 trees * 256 leaves
    gemm_kernel<300, true, false><<<262144 / TM, 256, 0, stream>>>(
        nullptr, wid, emb, W_leaf, nullptr, hA);

    // Tree levels: out node i <- rows (2i, 2i+1) of prev level (contiguous 600)
    bf16* cur = hA;
    bf16* nxt = hB;
    int nodes = 131072;  // level-1 total output nodes
    for (int l = 0; l < 8; l++) {
        gemm_kernel<600, false, true><<<nodes / TM, 256, 0, stream>>>(
            cur, nullptr, nullptr, W_h, b_h, nxt);
        bf16* t = cur; cur = nxt; nxt = t;
        nodes >>= 1;
    }
    // roots (1024 x 300 bf16) now in `cur` (== hA); view as (512, 600)

    cls_kernel<<<512, 64, 0, stream>>>(cur, W_cls, b_cls, outp);
}

// Round 5
// 468.462 us; speedup vs baseline: 12.2739x; 12.2739x over previous
//
#include <hip/hip_runtime.h>
#include <hip/hip_bf16.h>

typedef __hip_bfloat16 bf16;
typedef __attribute__((ext_vector_type(8))) short short8;   // 8 bf16 = 4 VGPRs
typedef __attribute__((ext_vector_type(4))) float float4v;  // MFMA C/D
typedef __attribute__((ext_vector_type(4))) short short4v;

__device__ __forceinline__ short f2bs(float x) {
    bf16 b = __float2bfloat16(x);
    return *reinterpret_cast<short*>(&b);
}
__device__ __forceinline__ float bs2f(short s) {
    bf16 b = *reinterpret_cast<bf16*>(&s);
    return __bfloat162float(b);
}

#define GLL16(g, l) __builtin_amdgcn_global_load_lds(                      \
    (const __attribute__((address_space(1))) void*)(g),                    \
    (__attribute__((address_space(3))) void*)(l), 16, 0, 0)

// ---------------- preprocessing: f32 -> padded bf16 layouts ----------------

// emb (50000,300) f32 -> emb_bf (50000,320) bf16, zero pad. 4 shorts/thread.
__global__ __launch_bounds__(256) void conv_emb(
    const float* __restrict__ src, short* __restrict__ dst)
{
    const int idx = blockIdx.x * 256 + threadIdx.x;      // 50000*80
    if (idx >= 50000 * 80) return;
    const int row = idx / 80;
    const int k4  = (idx - row * 80) * 4;
    short4v v;
#pragma unroll
    for (int j = 0; j < 4; ++j)
        v[j] = (k4 + j < 300) ? f2bs(src[(long)row * 300 + k4 + j]) : (short)0;
    *(short4v*)&dst[(long)row * 320 + k4] = v;
}

// W_leaf (300,300) -> Bleaf (320,320) bf16 zero-padded
__global__ __launch_bounds__(256) void conv_wleaf(
    const float* __restrict__ src, short* __restrict__ dst)
{
    const int idx = blockIdx.x * 256 + threadIdx.x;      // 320*320
    if (idx >= 320 * 320) return;
    const int row = idx / 320, k = idx - row * 320;
    dst[idx] = (row < 300 && k < 300) ? f2bs(src[row * 300 + k]) : (short)0;
}

// W_h (300,600) -> Bh (320,640): k'<300 -> k'; 320<=k'<620 -> k'-20; else 0
__global__ __launch_bounds__(256) void conv_wh(
    const float* __restrict__ src, short* __restrict__ dst)
{
    const int idx = blockIdx.x * 256 + threadIdx.x;      // 320*640
    if (idx >= 320 * 640) return;
    const int row = idx / 640, k = idx - row * 640;
    float v = 0.f;
    if (row < 300) {
        if (k < 300)                 v = src[row * 600 + k];
        else if (k >= 320 && k < 620) v = src[row * 600 + k - 20];
    }
    dst[idx] = f2bs(v);
}

// b_h (300,) -> biasp (320,) f32 zero-padded
__global__ __launch_bounds__(320) void conv_bias(
    const float* __restrict__ src, float* __restrict__ dst)
{
    const int i = threadIdx.x;
    if (i < 320) dst[i] = (i < 300) ? src[i] : 0.f;
}

// ---------------- MFMA GEMM ----------------
// out(M,320 bf16) = X(M,KE bf16) @ Wp(320,KE bf16)^T (+ biasp), KE in {320,640}.
// Block: 256 thr = 4 waves 2x2; tile M=128 x N=320 (full N). Wave: 64x160 =
// 4 M-tiles x 10 N-tiles of v_mfma_f32_16x16x32_bf16. Single-buffer LDS,
// global_load_lds width=16 staging, XOR k-quarter swizzle (2-way banks = free).
template <int KE, bool GATHER, bool BIAS>
__global__ __launch_bounds__(256, 2) void mfma_gemm(
    const short* __restrict__ Xsrc, const int* __restrict__ wid,
    const short* __restrict__ emb, const short* __restrict__ Wp,
    const float* __restrict__ biasp, short* __restrict__ out)
{
    __shared__ __align__(16) short As[128 * 32];   // [row][kq-slot] 64B rows
    __shared__ __align__(16) short Bs[320 * 32];

    const int tid  = threadIdx.x;
    const int lane = tid & 63;
    const int w    = tid >> 6;
    const int wm   = w >> 1, wn = w & 1;
    const long m0  = (long)blockIdx.x * 128;

    const int s_q   = lane & 3;     // this lane's LDS k-quarter slot
    const int r_off = lane >> 2;    // row within 16-row staging group

    // staging global pointers (chunk-invariant base)
    const char* gA[2];
#pragma unroll
    for (int j = 0; j < 2; ++j) {
        const int r = (w * 2 + j) * 16 + r_off;            // 0..127
        const int q = s_q ^ ((r >> 1) & 3);                // global k-quarter
        if (GATHER) {
            const long widx = wid[m0 + r];
            gA[j] = (const char*)emb + widx * 640 + q * 16;
        } else {
            gA[j] = (const char*)Xsrc + (m0 + r) * (long)(KE * 2) + q * 16;
        }
    }
    const char* gB[5];
#pragma unroll
    for (int j = 0; j < 5; ++j) {
        const int r = (w * 5 + j) * 16 + r_off;            // 0..319
        const int q = s_q ^ ((r >> 1) & 3);
        gB[j] = (const char*)Wp + r * (long)(KE * 2) + q * 16;
    }
    // LDS destinations (wave-uniform base; HW scatters lane*16)
    char* lA[2]; char* lB[5];
#pragma unroll
    for (int j = 0; j < 2; ++j) lA[j] = (char*)As + (w * 2 + j) * 1024;
#pragma unroll
    for (int j = 0; j < 5; ++j) lB[j] = (char*)Bs + (w * 5 + j) * 1024;

    // fragment LDS addresses (single buffer -> chunk-invariant)
    const short* fA[4];
#pragma unroll
    for (int t = 0; t < 4; ++t) {
        const int row = wm * 64 + t * 16 + (lane & 15);
        const int s   = (lane >> 4) ^ ((row >> 1) & 3);
        fA[t] = &As[row * 32 + s * 8];
    }
    const short* fB[10];
#pragma unroll
    for (int u = 0; u < 10; ++u) {
        const int n = wn * 160 + u * 16 + (lane & 15);
        const int s = (lane >> 4) ^ ((n >> 1) & 3);
        fB[u] = &Bs[n * 32 + s * 8];
    }

    float4v acc[4][10];
#pragma unroll
    for (int t = 0; t < 4; ++t)
#pragma unroll
        for (int u = 0; u < 10; ++u) acc[t][u] = (float4v)0.f;

    const int NCH = KE / 32;
    for (int kc = 0; kc < NCH; ++kc) {
        if (kc) __syncthreads();           // all waves done reading prev chunk
        const int off = kc * 64;
        GLL16(gA[0] + off, lA[0]);
        GLL16(gA[1] + off, lA[1]);
        GLL16(gB[0] + off, lB[0]);
        GLL16(gB[1] + off, lB[1]);
        GLL16(gB[2] + off, lB[2]);
        GLL16(gB[3] + off, lB[3]);
        GLL16(gB[4] + off, lB[4]);
        __syncthreads();                   // drains vmcnt -> LDS visible

        short8 a[4], b[10];
#pragma unroll
        for (int t = 0; t < 4; ++t) a[t] = *(const short8*)fA[t];
#pragma unroll
        for (int u = 0; u < 10; ++u) b[u] = *(const short8*)fB[u];
#pragma unroll
        for (int u = 0; u < 10; ++u)
#pragma unroll
            for (int t = 0; t < 4; ++t)
                acc[t][u] = __builtin_amdgcn_mfma_f32_16x16x32_bf16(
                    a[t], b[u], acc[t][u], 0, 0, 0);
    }

    // epilogue: C/D layout col=lane&15, row=(lane>>4)*4+reg
#pragma unroll
    for (int u = 0; u < 10; ++u) {
        const int c = wn * 160 + u * 16 + (lane & 15);
        const float bv = BIAS ? biasp[c] : 0.f;
#pragma unroll
        for (int t = 0; t < 4; ++t) {
            const long mb = m0 + wm * 64 + t * 16 + (lane >> 4) * 4;
#pragma unroll
            for (int r4 = 0; r4 < 4; ++r4)
                out[(mb + r4) * 320 + c] = f2bs(acc[t][u][r4] + bv);
        }
    }
}

// ---------------- classifier ----------------
// roots: 512 rows of 640 bf16 (pads at 300..320, 620..640). One wave per row.
__global__ __launch_bounds__(64) void cls_kernel(
    const short* __restrict__ roots, const float* __restrict__ W_cls,
    const float* __restrict__ b_cls, float* __restrict__ out)
{
    const int b    = blockIdx.x;
    const int lane = threadIdx.x;
    const short* row = roots + (long)b * 640;

    float a0 = 0.f, a1 = 0.f, a2 = 0.f;
#pragma unroll
    for (int i = 0; i < 10; ++i) {
        const int k = lane + 64 * i;
        if (k < 600) {
            const int col = (k < 300) ? k : k + 20;
            const float f = 1.f / (1.f + __expf(-bs2f(row[col])));
            a0 += f * W_cls[k];
            a1 += f * W_cls[600 + k];
            a2 += f * W_cls[1200 + k];
        }
    }
#pragma unroll
    for (int off = 32; off > 0; off >>= 1) {
        a0 += __shfl_down(a0, off);
        a1 += __shfl_down(a1, off);
        a2 += __shfl_down(a2, off);
    }
    if (lane == 0) {
        const float l0 = a0 + b_cls[0];
        const float l1 = a1 + b_cls[1];
        const float l2 = a2 + b_cls[2];
        const float m  = fmaxf(l0, fmaxf(l1, l2));
        const float s  = __expf(l0 - m) + __expf(l1 - m) + __expf(l2 - m);
        const float ls = m + __logf(s);
        out[b * 3 + 0] = l0 - ls;
        out[b * 3 + 1] = l1 - ls;
        out[b * 3 + 2] = l2 - ls;
    }
}

extern "C" void kernel_launch(void* const* d_in, const int* in_sizes, int n_in,
                              void* d_out, int out_size, void* d_ws, size_t ws_size,
                              hipStream_t stream)
{
    const int*   wid    = (const int*)d_in[0];     // (512,2,256) int32
    const float* emb    = (const float*)d_in[1];   // (50000,300) f32
    const float* W_leaf = (const float*)d_in[2];   // (300,300)
    const float* W_h    = (const float*)d_in[3];   // (300,600)
    const float* b_h    = (const float*)d_in[4];   // (300,)
    const float* W_cls  = (const float*)d_in[5];   // (3,600)
    const float* b_cls  = (const float*)d_in[6];   // (3,)
    float* outp = (float*)d_out;                   // (512,3) f32

    (void)in_sizes; (void)n_in; (void)out_size; (void)ws_size;

    // ws layout (peak 252,273,920 B < 256 MiB; R4's 284 MB layout faulted):
    //   hA     @ 0           : 262144*320*2 = 167,772,160
    //   hB     @ 167,772,160 : 131072*320*2 =  83,886,080
    //   emb_bf @ 167,772,160 : 50000*320*2  =  32,000,000  (ALIASES hB: dead
    //            after leaf GEMM; hB first written by L1, which runs later)
    //   Bleaf  @ 251,658,240 : 320*320*2    =     204,800
    //   Bh     @ 251,863,040 : 320*640*2    =     409,600
    //   biasp  @ 252,272,640 : 320*4        =       1,280
    char* ws = (char*)d_ws;
    short* hA     = (short*)(ws);
    short* hB     = (short*)(ws + 167772160);
    short* emb_bf = (short*)(ws + 167772160);
    short* Bleaf  = (short*)(ws + 251658240);
    short* Bh     = (short*)(ws + 251863040);
    float* biasp  = (float*)(ws + 252272640);

    conv_emb  <<<(50000 * 80 + 255) / 256, 256, 0, stream>>>(emb, emb_bf);
    conv_wleaf<<<(320 * 320) / 256, 256, 0, stream>>>(W_leaf, Bleaf);
    conv_wh   <<<(320 * 640) / 256, 256, 0, stream>>>(W_h, Bh);
    conv_bias <<<1, 320, 0, stream>>>(b_h, biasp);

    // Leaf: M = 262144, K' = 320 (gather rows of emb_bf)
    mfma_gemm<320, true, false><<<262144 / 128, 256, 0, stream>>>(
        nullptr, wid, emb_bf, Bleaf, biasp, hA);

    // Tree: node m reads prev rows 2m,2m+1 = contiguous 640 bf16 (pads align
    // with Bh's zero k-columns). K' = 640.  L1 reads hA -> writes hB (emb_bf
    // space, now dead); then ping-pong.
    short* cur = hA;
    short* nxt = hB;
    int nodes = 131072;
    for (int l = 0; l < 8; ++l) {
        mfma_gemm<640, false, true><<<nodes / 128, 256, 0, stream>>>(
            cur, nullptr, nullptr, Bh, biasp, nxt);
        short* t = cur; cur = nxt; nxt = t;
        nodes >>= 1;
    }
    // roots: cur == hA, 1024 rows x 320 -> 512 x 640 view

    cls_kernel<<<512, 64, 0, stream>>>(cur, W_cls, b_cls, outp);
}